// Round 2
// baseline (555.871 us; speedup 1.0000x reference)
//
#include <hip/hip_runtime.h>
#include <math.h>

// ---------------- problem constants (fixed by reference module) -------------
#define NB      2          // batch
#define LQ      12240      // queries
#define LEN_IN  12240      // value length
#define CMODEL  256
#define MHEADS  8
#define NLEV    4
#define NPTS    4
#define DHEAD   32         // CMODEL / MHEADS
#define MROWS   (NB * LQ)  // 24480

__device__ __constant__ int c_H[4]  = {96, 48, 24, 12};
__device__ __constant__ int c_W[4]  = {96, 48, 24, 12};
__device__ __constant__ int c_ST[4] = {0, 9216, 11520, 12096};

// ---------------- fp32 tiled GEMM with bias: C = A(MxK) * B(KxN) + bias -----
// BM=64 BN=64 BK=16, 256 threads, 4x4 microtile per thread.
template<int BM, int BN, int BK, int TM, int TN>
__global__ __launch_bounds__(256)
void sgemm_bias(const float* __restrict__ A, const float* __restrict__ B,
                const float* __restrict__ bias, float* __restrict__ C,
                int M, int N, int K)
{
    __shared__ float As[BK][BM + 4];
    __shared__ float Bs[BK][BN + 4];

    const int tid = threadIdx.x;
    const int bm  = blockIdx.y * BM;
    const int bn  = blockIdx.x * BN;
    const int tr  = (tid >> 4) * TM;   // 0..60
    const int tc  = (tid & 15) * TN;   // 0..60

    float acc[TM][TN];
#pragma unroll
    for (int i = 0; i < TM; ++i)
#pragma unroll
        for (int j = 0; j < TN; ++j) acc[i][j] = 0.f;

    for (int k0 = 0; k0 < K; k0 += BK) {
        // A tile: BM x BK (64x16) = 1024 floats, float4 per thread along K
        {
            int r  = tid >> 2;          // 0..63
            int c4 = (tid & 3) * 4;     // 0,4,8,12
            int row = bm + r;
            float4 v = make_float4(0.f, 0.f, 0.f, 0.f);
            if (row < M) v = *(const float4*)&A[(long)row * K + k0 + c4];
            As[c4 + 0][r] = v.x;
            As[c4 + 1][r] = v.y;
            As[c4 + 2][r] = v.z;
            As[c4 + 3][r] = v.w;
        }
        // B tile: BK x BN (16x64) = 1024 floats, float4 per thread along N
        {
            int r  = tid >> 4;          // 0..15
            int c4 = (tid & 15) * 4;    // 0..60
            float4 v = *(const float4*)&B[(long)(k0 + r) * N + bn + c4];
            *(float4*)&Bs[r][c4] = v;
        }
        __syncthreads();

#pragma unroll
        for (int k = 0; k < BK; ++k) {
            float a[TM], b[TN];
#pragma unroll
            for (int i = 0; i < TM; ++i) a[i] = As[k][tr + i];
#pragma unroll
            for (int j = 0; j < TN; ++j) b[j] = Bs[k][tc + j];
#pragma unroll
            for (int i = 0; i < TM; ++i)
#pragma unroll
                for (int j = 0; j < TN; ++j) acc[i][j] += a[i] * b[j];
        }
        __syncthreads();
    }

#pragma unroll
    for (int i = 0; i < TM; ++i) {
        int row = bm + tr + i;
        if (row >= M) continue;
#pragma unroll
        for (int j = 0; j < TN; ++j) {
            int col = bn + tc + j;
            C[(long)row * N + col] = acc[i][j] + bias[col];
        }
    }
}

// ---------------- sampling + softmax + attention-weighted sum ---------------
// One item = (n, q, m). 32 lanes per item (lane = channel d). 8 items/block.
__global__ __launch_bounds__(256)
void msda_sample(const float* __restrict__ value,    // (N, LEN_IN, M, D)
                 const float* __restrict__ offsets,  // (N, Lq, M, L, P, 2)
                 const float* __restrict__ logits,   // (N, Lq, M, L*P)
                 const float* __restrict__ refpts,   // (N, Lq, L, 2)
                 float* __restrict__ msda)           // (N, Lq, M*D)
{
    const int  itemInBlock = threadIdx.x >> 5;           // 0..7
    const int  d           = threadIdx.x & 31;
    const long item        = (long)blockIdx.x * 8 + itemInBlock;
    const long totalItems  = (long)NB * LQ * MHEADS;
    if (item >= totalItems) return;

    const int  m  = (int)(item & (MHEADS - 1));
    const long nq = item >> 3;                           // n*Lq + q
    const int  n  = (int)(nq / LQ);

    // softmax over 16 logits (redundant per lane; loads broadcast)
    const float* lg = logits + (nq * MHEADS + m) * (NLEV * NPTS);
    float l[16];
    float mx = -1e30f;
#pragma unroll
    for (int j = 0; j < 16; ++j) { l[j] = lg[j]; mx = fmaxf(mx, l[j]); }
    float s = 0.f;
#pragma unroll
    for (int j = 0; j < 16; ++j) { l[j] = __expf(l[j] - mx); s += l[j]; }
    const float inv = 1.f / s;

    const float* off = offsets + (nq * MHEADS + m) * (NLEV * NPTS * 2);
    const float* rp  = refpts + nq * (NLEV * 2);
    const float* vb  = value + (long)n * LEN_IN * CMODEL + m * DHEAD + d;

    float acc = 0.f;
#pragma unroll
    for (int lvl = 0; lvl < NLEV; ++lvl) {
        const int H = c_H[lvl], W = c_W[lvl], st = c_ST[lvl];
        const float rx = rp[lvl * 2 + 0];
        const float ry = rp[lvl * 2 + 1];
        const float* base = vb + (long)st * CMODEL;
#pragma unroll
        for (int p = 0; p < NPTS; ++p) {
            const int j = lvl * NPTS + p;
            const float w_attn = l[j] * inv;
            const float lx = rx + off[j * 2 + 0] * (1.0f / (float)W);
            const float ly = ry + off[j * 2 + 1] * (1.0f / (float)H);
            // grid_sample coords (align_corners=False): x = loc*W - 0.5
            const float x = lx * (float)W - 0.5f;
            const float y = ly * (float)H - 0.5f;
            const float x0f = floorf(x), y0f = floorf(y);
            const int   x0 = (int)x0f,  y0 = (int)y0f;
            const float wx1 = x - x0f, wx0 = 1.f - wx1;
            const float wy1 = y - y0f, wy0 = 1.f - wy1;

            const bool xv0 = (x0 >= 0) & (x0 < W);
            const bool xv1 = (x0 + 1 >= 0) & (x0 + 1 < W);
            const bool yv0 = (y0 >= 0) & (y0 < H);
            const bool yv1 = (y0 + 1 >= 0) & (y0 + 1 < H);
            const int xc0 = min(max(x0, 0), W - 1);
            const int xc1 = min(max(x0 + 1, 0), W - 1);
            const int yc0 = min(max(y0, 0), H - 1);
            const int yc1 = min(max(y0 + 1, 0), H - 1);

            float v00 = 0.f, v01 = 0.f, v10 = 0.f, v11 = 0.f;
            if (yv0) {
                const float* rowp = base + (long)yc0 * W * CMODEL;
                if (xv0) v00 = rowp[(long)xc0 * CMODEL];
                if (xv1) v01 = rowp[(long)xc1 * CMODEL];
            }
            if (yv1) {
                const float* rowp = base + (long)yc1 * W * CMODEL;
                if (xv0) v10 = rowp[(long)xc0 * CMODEL];
                if (xv1) v11 = rowp[(long)xc1 * CMODEL];
            }
            acc += w_attn * (wy0 * (wx0 * v00 + wx1 * v01) +
                             wy1 * (wx0 * v10 + wx1 * v11));
        }
    }
    msda[nq * CMODEL + m * DHEAD + d] = acc;
}

// ---------------------------------------------------------------------------
extern "C" void kernel_launch(void* const* d_in, const int* in_sizes, int n_in,
                              void* d_out, int out_size, void* d_ws, size_t ws_size,
                              hipStream_t stream)
{
    const float* query = (const float*)d_in[0];
    const float* refp  = (const float*)d_in[1];
    const float* inpf  = (const float*)d_in[2];
    // d_in[3], d_in[4]: spatial shapes / level starts (compile-time constants)
    const float* Wv    = (const float*)d_in[5];
    const float* bv    = (const float*)d_in[6];
    const float* Wo    = (const float*)d_in[7];
    const float* bo    = (const float*)d_in[8];
    const float* Wa    = (const float*)d_in[9];
    const float* ba    = (const float*)d_in[10];
    const float* Wout  = (const float*)d_in[11];
    const float* bout  = (const float*)d_in[12];
    float* out = (float*)d_out;

    // workspace layout (floats): value | offsets | logits | msda  (~88 MB)
    float* ws     = (float*)d_ws;
    float* value  = ws;                               // 24480*256
    float* offs   = value  + (long)MROWS * CMODEL;    // 24480*256
    float* lgts   = offs   + (long)MROWS * CMODEL;    // 24480*128
    float* msda   = lgts   + (long)MROWS * 128;       // 24480*256

    const dim3 blk(256);
    const int gy = (MROWS + 63) / 64;   // 383

    // 1) value = input_flatten @ Wv + bv
    sgemm_bias<64,64,16,4,4><<<dim3(CMODEL/64, gy), blk, 0, stream>>>(
        inpf, Wv, bv, value, MROWS, CMODEL, CMODEL);
    // 2) offsets = query @ Wo + bo
    sgemm_bias<64,64,16,4,4><<<dim3(CMODEL/64, gy), blk, 0, stream>>>(
        query, Wo, bo, offs, MROWS, CMODEL, CMODEL);
    // 3) logits = query @ Wa + ba
    sgemm_bias<64,64,16,4,4><<<dim3(128/64, gy), blk, 0, stream>>>(
        query, Wa, ba, lgts, MROWS, 128, CMODEL);
    // 4) sampling
    {
        const long items = (long)NB * LQ * MHEADS;    // 195840
        msda_sample<<<(int)((items + 7) / 8), blk, 0, stream>>>(
            value, offs, lgts, refp, msda);
    }
    // 5) out = msda @ Wout + bout
    sgemm_bias<64,64,16,4,4><<<dim3(CMODEL/64, gy), blk, 0, stream>>>(
        msda, Wout, bout, out, MROWS, CMODEL, CMODEL);
}

// Round 4
// 383.953 us; speedup vs baseline: 1.4478x; 1.4478x over previous
//
#include <hip/hip_runtime.h>
#include <hip/hip_bf16.h>
#include <math.h>

// ---------------- problem constants (fixed by reference module) -------------
#define NB      2
#define LQ      12240
#define LEN_IN  12240
#define CMODEL  256
#define KDIM    256
#define MHEADS  8
#define NLEV    4
#define NPTS    4
#define DHEAD   32
#define MROWS   (NB * LQ)   // 24480

typedef __attribute__((ext_vector_type(8))) short  bf16x8;
typedef __attribute__((ext_vector_type(4))) float  f32x4;

__device__ __constant__ int c_H[4]  = {96, 48, 24, 12};
__device__ __constant__ int c_W[4]  = {96, 48, 24, 12};
__device__ __constant__ int c_ST[4] = {0, 9216, 11520, 12096};

// ---------- transpose + f32->bf16: W [K][N] f32  ->  Wt [N][K] bf16 ---------
__global__ __launch_bounds__(256)
void transpose_bf16(const float* __restrict__ W, __hip_bfloat16* __restrict__ Wt,
                    int K, int N)
{
    __shared__ float t[32][33];
    const int n0 = blockIdx.x * 32, k0 = blockIdx.y * 32;
    const int c = threadIdx.x & 31, r0 = threadIdx.x >> 5;   // r0: 0..7
#pragma unroll
    for (int i = 0; i < 4; ++i) {
        int r = r0 + i * 8;
        t[r][c] = W[(long)(k0 + r) * N + n0 + c];
    }
    __syncthreads();
#pragma unroll
    for (int i = 0; i < 4; ++i) {
        int r = r0 + i * 8;
        Wt[(long)(n0 + r) * K + k0 + c] = __float2bfloat16(t[c][r]);
    }
}

// ---------- bf16 MFMA GEMM: C[M][N] = A[M][256]_f32 * Bt[N][256]_bf16 + bias
// 128x128 tile, BK=64, 256 threads = 4 waves (2x2), 64x64 per wave,
// mfma_f32_16x16x32_bf16, 4x4 fragments per wave.
__global__ __launch_bounds__(256)
void mfma_gemm(const float* __restrict__ A,
               const __hip_bfloat16* __restrict__ Bt,
               const float* __restrict__ bias,
               float* __restrict__ C,
               int M, int N)
{
    constexpr int BK   = 64;
    constexpr int LDSP = BK + 8;            // pad 8 bf16 = 16B -> 144B row stride
    __shared__ __hip_bfloat16 As[128][LDSP];
    __shared__ __hip_bfloat16 Bs[128][LDSP];

    const int tid  = threadIdx.x;
    const int lane = tid & 63;
    const int wave = tid >> 6;
    const int wm   = wave >> 1, wn = wave & 1;
    const int bm   = blockIdx.y * 128;
    const int bn   = blockIdx.x * 128;

    f32x4 acc[4][4];
#pragma unroll
    for (int i = 0; i < 4; ++i)
#pragma unroll
        for (int j = 0; j < 4; ++j) acc[i][j] = (f32x4)0.f;

    // staging coords
    const int srowA = tid >> 4;             // 0..15
    const int scolA = (tid & 15) * 4;       // 0..60 (float4 along K)
    const int srowB = tid >> 3;             // 0..31
    const int scolB = (tid & 7) * 8;        // 0..56 (bf16x8 along K)

    for (int k0 = 0; k0 < KDIM; k0 += BK) {
        // A: 128 rows x 64 k, f32 -> bf16
#pragma unroll
        for (int i = 0; i < 8; ++i) {
            int row  = srowA + i * 16;
            int grow = bm + row; if (grow > M - 1) grow = M - 1;
            float4 v = *(const float4*)&A[(long)grow * KDIM + k0 + scolA];
            ushort4 h;
            __hip_bfloat16 hx = __float2bfloat16(v.x);
            __hip_bfloat16 hy = __float2bfloat16(v.y);
            __hip_bfloat16 hz = __float2bfloat16(v.z);
            __hip_bfloat16 hw = __float2bfloat16(v.w);
            h.x = *(unsigned short*)&hx; h.y = *(unsigned short*)&hy;
            h.z = *(unsigned short*)&hz; h.w = *(unsigned short*)&hw;
            *(ushort4*)&As[row][scolA] = h;
        }
        // B: 128 cols x 64 k, already bf16 (N is a multiple of 128 -> no clamp)
#pragma unroll
        for (int i = 0; i < 4; ++i) {
            int row = srowB + i * 32;
            bf16x8 v = *(const bf16x8*)&Bt[(long)(bn + row) * KDIM + k0 + scolB];
            *(bf16x8*)&Bs[row][scolB] = v;
        }
        __syncthreads();

#pragma unroll
        for (int kc = 0; kc < BK; kc += 32) {
            const int krd = kc + ((lane >> 4) << 3);
            bf16x8 a[4], b[4];
#pragma unroll
            for (int mi = 0; mi < 4; ++mi)
                a[mi] = *(const bf16x8*)&As[wm * 64 + mi * 16 + (lane & 15)][krd];
#pragma unroll
            for (int nj = 0; nj < 4; ++nj)
                b[nj] = *(const bf16x8*)&Bs[wn * 64 + nj * 16 + (lane & 15)][krd];
#pragma unroll
            for (int mi = 0; mi < 4; ++mi)
#pragma unroll
                for (int nj = 0; nj < 4; ++nj)
                    acc[mi][nj] = __builtin_amdgcn_mfma_f32_16x16x32_bf16(
                        a[mi], b[nj], acc[mi][nj], 0, 0, 0);
        }
        __syncthreads();
    }

    // epilogue: C/D layout col=lane&15, row=(lane>>4)*4+reg  [m89/m91]
    const int colb = lane & 15;
    const int rowb = (lane >> 4) * 4;
#pragma unroll
    for (int mi = 0; mi < 4; ++mi) {
#pragma unroll
        for (int r = 0; r < 4; ++r) {
            int grow = bm + wm * 64 + mi * 16 + rowb + r;
            if (grow >= M) continue;
#pragma unroll
            for (int nj = 0; nj < 4; ++nj) {
                int gcol = bn + wn * 64 + nj * 16 + colb;
                C[(long)grow * N + gcol] = acc[mi][nj][r] + bias[gcol];
            }
        }
    }
}

// ---------------- sampling: 8 lanes/item, float4 over D=32 ------------------
__global__ __launch_bounds__(256)
void msda_sample4(const float* __restrict__ value,    // (N, LEN_IN, M*D)
                  const float* __restrict__ offsets,  // (N, Lq, M, L, P, 2)
                  const float* __restrict__ logits,   // (N, Lq, M, 16)
                  const float* __restrict__ refpts,   // (N, Lq, L, 2)
                  float* __restrict__ msda)           // (N, Lq, M*D)
{
    const int  g    = threadIdx.x & 7;            // channel group (4 floats)
    const int  ib   = threadIdx.x >> 3;           // 0..31 items per block
    const long item = (long)blockIdx.x * 32 + ib; // grid exact: 195840/32=6120
    const int  m    = (int)(item & (MHEADS - 1));
    const long nq   = item >> 3;
    const int  n    = (int)(nq / LQ);

    // softmax over 16 logits (redundant across 8 lanes; broadcast loads)
    const float* lg = logits + (nq * MHEADS + m) * 16;
    float l[16];
    float mx = -1e30f;
#pragma unroll
    for (int j4 = 0; j4 < 4; ++j4) {
        float4 v = *(const float4*)&lg[j4 * 4];
        l[j4*4+0] = v.x; l[j4*4+1] = v.y; l[j4*4+2] = v.z; l[j4*4+3] = v.w;
    }
#pragma unroll
    for (int j = 0; j < 16; ++j) mx = fmaxf(mx, l[j]);
    float s = 0.f;
#pragma unroll
    for (int j = 0; j < 16; ++j) { l[j] = __expf(l[j] - mx); s += l[j]; }
    const float inv = 1.f / s;

    const float* off = offsets + (nq * MHEADS + m) * 32;
    const float* rp  = refpts + nq * (NLEV * 2);
    const float* vb  = value + (long)n * LEN_IN * CMODEL + m * DHEAD + g * 4;

    f32x4 acc = (f32x4)0.f;
#pragma unroll
    for (int lvl = 0; lvl < NLEV; ++lvl) {
        const int H = c_H[lvl], W = c_W[lvl], st = c_ST[lvl];
        const float2 r2 = *(const float2*)&rp[lvl * 2];
        const float rxW = r2.x * (float)W;
        const float ryH = r2.y * (float)H;
        const float* base = vb + (long)st * CMODEL;
#pragma unroll
        for (int p = 0; p < NPTS; ++p) {
            const int j = lvl * NPTS + p;
            const float w_attn = l[j] * inv;
            const float2 o2 = *(const float2*)&off[j * 2];
            // x = ((rx + ox/W) * W) - 0.5 = rx*W + ox - 0.5
            const float x = rxW + o2.x - 0.5f;
            const float y = ryH + o2.y - 0.5f;
            const float x0f = floorf(x), y0f = floorf(y);
            const int   x0 = (int)x0f,  y0 = (int)y0f;
            const float wx1 = x - x0f, wx0 = 1.f - wx1;
            const float wy1 = y - y0f, wy0 = 1.f - wy1;

            const bool xv0 = (x0 >= 0) & (x0 < W);
            const bool xv1 = (x0 + 1 >= 0) & (x0 + 1 < W);
            const bool yv0 = (y0 >= 0) & (y0 < H);
            const bool yv1 = (y0 + 1 >= 0) & (y0 + 1 < H);
            const int xc0 = min(max(x0, 0), W - 1);
            const int xc1 = min(max(x0 + 1, 0), W - 1);
            const int yc0 = min(max(y0, 0), H - 1);
            const int yc1 = min(max(y0 + 1, 0), H - 1);

            f32x4 v00 = (f32x4)0.f, v01 = (f32x4)0.f;
            f32x4 v10 = (f32x4)0.f, v11 = (f32x4)0.f;
            if (yv0) {
                const float* rowp = base + (long)yc0 * W * CMODEL;
                if (xv0) v00 = *(const f32x4*)&rowp[(long)xc0 * CMODEL];
                if (xv1) v01 = *(const f32x4*)&rowp[(long)xc1 * CMODEL];
            }
            if (yv1) {
                const float* rowp = base + (long)yc1 * W * CMODEL;
                if (xv0) v10 = *(const f32x4*)&rowp[(long)xc0 * CMODEL];
                if (xv1) v11 = *(const f32x4*)&rowp[(long)xc1 * CMODEL];
            }
            acc += w_attn * (wy0 * (wx0 * v00 + wx1 * v01) +
                             wy1 * (wx0 * v10 + wx1 * v11));
        }
    }
    *(f32x4*)&msda[nq * CMODEL + m * DHEAD + g * 4] = acc;
}

// ---------------------------------------------------------------------------
extern "C" void kernel_launch(void* const* d_in, const int* in_sizes, int n_in,
                              void* d_out, int out_size, void* d_ws, size_t ws_size,
                              hipStream_t stream)
{
    const float* query = (const float*)d_in[0];
    const float* refp  = (const float*)d_in[1];
    const float* inpf  = (const float*)d_in[2];
    const float* Wv    = (const float*)d_in[5];
    const float* bv    = (const float*)d_in[6];
    const float* Wo    = (const float*)d_in[7];
    const float* bo    = (const float*)d_in[8];
    const float* Wa    = (const float*)d_in[9];
    const float* ba    = (const float*)d_in[10];
    const float* Wout  = (const float*)d_in[11];
    const float* bout  = (const float*)d_in[12];
    float* out = (float*)d_out;

    // ws layout (floats): value | offs | lgts | msda | bf16 weight buffers
    float* ws    = (float*)d_ws;
    float* value = ws;                                // 24480*256
    float* offs  = value + (long)MROWS * CMODEL;      // 24480*256
    float* lgts  = offs  + (long)MROWS * CMODEL;      // 24480*128
    float* msda  = lgts  + (long)MROWS * 128;         // 24480*256
    __hip_bfloat16* Wtv = (__hip_bfloat16*)(msda + (long)MROWS * CMODEL);
    __hip_bfloat16* Wto = Wtv + 256 * 256;
    __hip_bfloat16* Wta = Wto + 256 * 256;
    __hip_bfloat16* Wtt = Wta + 128 * 256;            // Wout^T

    const dim3 blk(256);

    // 0) weight transposes (f32 [K][N] -> bf16 [N][K])
    transpose_bf16<<<dim3(8, 8), blk, 0, stream>>>(Wv,   Wtv, 256, 256);
    transpose_bf16<<<dim3(8, 8), blk, 0, stream>>>(Wo,   Wto, 256, 256);
    transpose_bf16<<<dim3(4, 8), blk, 0, stream>>>(Wa,   Wta, 256, 128);
    transpose_bf16<<<dim3(8, 8), blk, 0, stream>>>(Wout, Wtt, 256, 256);

    const int gy = (MROWS + 127) / 128;  // 192

    // 1) value = input_flatten @ Wv + bv
    mfma_gemm<<<dim3(2, gy), blk, 0, stream>>>(inpf, Wtv, bv, value, MROWS, 256);
    // 2) offsets = query @ Wo + bo
    mfma_gemm<<<dim3(2, gy), blk, 0, stream>>>(query, Wto, bo, offs, MROWS, 256);
    // 3) logits = query @ Wa + ba
    mfma_gemm<<<dim3(1, gy), blk, 0, stream>>>(query, Wta, ba, lgts, MROWS, 128);
    // 4) sampling
    msda_sample4<<<dim3((NB * LQ * MHEADS) / 32), blk, 0, stream>>>(
        value, offs, lgts, refp, msda);
    // 5) out = msda @ Wout + bout
    mfma_gemm<<<dim3(2, gy), blk, 0, stream>>>(msda, Wtt, bout, out, MROWS, 256);
}